// Round 5
// baseline (754.985 us; speedup 1.0000x reference)
//
#include <hip/hip_runtime.h>
#include <hip/hip_bf16.h>
#include <math.h>

// H2R detector: score map -> 3x3 NMS peaks -> per-batch top-1000 -> ROIs.
// [B=32,1,512,512] fp32 inputs; out = rois[32,1000,5] ++ scores[32,1000]
// ++ valid[32,1000] = 224000 floats.
//
// ROUND 5 THEORY: ref=np is a numpy transliteration; sigmoid = 1/(1+np.exp(-x))
// where np.exp (fp32 SIMD path) is the Cephes expf:
//   m = rint(x*log2e)                       (mul then rint, round-nearest-even)
//   r = fma(m,-0.693359375,x); r = fma(m, 2.12194440e-4, r)
//   P = Horner FMA over {1.9875691500e-4 ... 5.0000001201e-1}
//   e = (fma(P, r*r, r) + 1) * 2^m
// Division / mul / sub are single-rounding fp32 (numpy = one ufunc per op).
// We replicate op-for-op with contraction disabled so the top-k ORDERING
// matches bit-exactly; values only need the 2%-of-range threshold.

#define B_   32
#define H_   512
#define W_   512
#define HW_  (H_ * W_)
#define K_   1000
#define NB_  16384      // histogram buckets = float_bits >> 18
#define CANDCAP_ 4096   // per-batch candidate capacity (power of 2)
#define TILE_ 32

// ---- numpy SIMD (Cephes) fp32 exp replica ----------------------------------
__device__ __forceinline__ float np_expf(float x) {
#pragma clang fp contract(off)
    const float log2e = 1.44269504088896341f;     // f32: 1.4426950216293335
    float z = x * log2e;                          // separate mul
    float m = rintf(z);                           // v_rndne: half-to-even
    float r = fmaf(m, -0.693359375f, x);          // ln2_hi (exact product)
    r = fmaf(m, 2.12194440e-4f, r);               // -ln2_lo
    float r2 = r * r;
    float p = fmaf(1.9875691500e-4f, r, 1.3981999507e-3f);
    p = fmaf(p, r, 8.3334519073e-3f);
    p = fmaf(p, r, 4.1665795894e-2f);
    p = fmaf(p, r, 1.6666665459e-1f);
    p = fmaf(p, r, 5.0000001201e-1f);
    p = fmaf(p, r2, r);                           // P*r^2 + r
    p = p + 1.0f;                                 // + 1
    // scale by 2^m (m in [-130,130] clamped; our inputs give |m|<=10)
    int mi = (int)m;
    float sc = __int_as_float((127 + mi) << 23);
    return p * sc;
}

__device__ __forceinline__ float sigmoid_np(float x) {
#pragma clang fp contract(off)
    float e = np_expf(-x);
    float d = 1.0f + e;
    return 1.0f / d;                              // IEEE CR fp32 divide
}

// score = sigmoid(r)^2 * (1 - 0.35*sigmoid(u)), one rounding per op
__device__ __forceinline__ float score_ref(float r, float u) {
#pragma clang fp contract(off)
    float s  = sigmoid_np(r);
    float s2 = s * s;                             // power(s, 2.0)
    float su = sigmoid_np(u);
    float t  = 0.35f * su;
    float m  = 1.0f - t;
    return s2 * m;
}

__device__ __forceinline__ float sigmoid_fast(float x) {  // box geometry only
    return 1.0f / (1.0f + __expf(-x));
}

// ---- Pass A: score + 3x3 peak test -> histogram ----------------------------
__global__ __launch_bounds__(256) void hist_kernel(
    const float* __restrict__ route, const float* __restrict__ unc,
    unsigned int* __restrict__ hist)
{
    __shared__ float sm[34][36];
    const int b  = blockIdx.z;
    const int bx = blockIdx.x * TILE_, by = blockIdx.y * TILE_;
    const float* rb = route + (size_t)b * HW_;
    const float* ub = unc   + (size_t)b * HW_;

    for (int t = threadIdx.x; t < 34 * 34; t += 256) {
        int ly = t / 34, lx = t - ly * 34;
        int gy = by + ly - 1, gx = bx + lx - 1;
        float val = -INFINITY;
        if ((unsigned)gy < (unsigned)H_ && (unsigned)gx < (unsigned)W_)
            val = score_ref(rb[gy * W_ + gx], ub[gy * W_ + gx]);
        sm[ly][lx] = val;
    }
    __syncthreads();

    for (int t = threadIdx.x; t < TILE_ * TILE_; t += 256) {
        int oy = t >> 5, ox = t & 31;
        float v = sm[oy + 1][ox + 1];
        float m =        sm[oy    ][ox    ];
        m = fmaxf(m,     sm[oy    ][ox + 1]);
        m = fmaxf(m,     sm[oy    ][ox + 2]);
        m = fmaxf(m,     sm[oy + 1][ox    ]);
        m = fmaxf(m,     sm[oy + 1][ox + 2]);
        m = fmaxf(m,     sm[oy + 2][ox    ]);
        m = fmaxf(m,     sm[oy + 2][ox + 1]);
        m = fmaxf(m,     sm[oy + 2][ox + 2]);
        if (v >= m)
            atomicAdd(&hist[b * NB_ + (__float_as_uint(v) >> 18)], 1u);
    }
}

// ---- Pass B: per-batch threshold bucket T ----------------------------------
__global__ __launch_bounds__(1024) void thresh_kernel(
    const unsigned int* __restrict__ hist, unsigned int* __restrict__ thresh)
{
    __shared__ unsigned int chunk[1024];
    __shared__ int warp_s[16];
    __shared__ int sh_sum, sh_T;

    const int b = blockIdx.x, tid = threadIdx.x;
    const int lane = tid & 63, wid = tid >> 6;
    if (tid == 0) sh_T = 0;

    int total = 0;
    for (int c = NB_ / 1024 - 1; c >= 0; --c) {
        unsigned int hv = hist[b * NB_ + c * 1024 + tid];
        chunk[tid] = hv;
        int v = (int)hv;
        #pragma unroll
        for (int off = 32; off > 0; off >>= 1) v += __shfl_down(v, off, 64);
        if (lane == 0) warp_s[wid] = v;
        __syncthreads();
        if (tid == 0) {
            int s = 0;
            #pragma unroll
            for (int w = 0; w < 16; ++w) s += warp_s[w];
            sh_sum = s;
        }
        __syncthreads();
        int s = sh_sum;
        __syncthreads();
        if (total + s < K_) { total += s; continue; }
        if (tid == 0) {                   // crossing inside this chunk
            int acc = total, t = c * 1024;
            for (int i = 1023; i >= 0; --i) {
                acc += (int)chunk[i];
                if (acc >= K_) { t = c * 1024 + i; break; }
            }
            sh_T = t;
        }
        break;
    }
    __syncthreads();
    if (tid == 0) thresh[b] = (unsigned int)sh_T;
}

// ---- Pass C: recompute, gather candidates with bucket >= T -----------------
__global__ __launch_bounds__(256) void cand_kernel(
    const float* __restrict__ route, const float* __restrict__ unc,
    const unsigned int* __restrict__ thresh,
    unsigned long long* __restrict__ cand, int* __restrict__ cand_cnt)
{
    __shared__ float sm[34][36];
    const int b  = blockIdx.z;
    const int bx = blockIdx.x * TILE_, by = blockIdx.y * TILE_;
    const unsigned int T = thresh[b];
    const float* rb = route + (size_t)b * HW_;
    const float* ub = unc   + (size_t)b * HW_;

    for (int t = threadIdx.x; t < 34 * 34; t += 256) {
        int ly = t / 34, lx = t - ly * 34;
        int gy = by + ly - 1, gx = bx + lx - 1;
        float val = -INFINITY;
        if ((unsigned)gy < (unsigned)H_ && (unsigned)gx < (unsigned)W_)
            val = score_ref(rb[gy * W_ + gx], ub[gy * W_ + gx]);
        sm[ly][lx] = val;
    }
    __syncthreads();

    for (int t = threadIdx.x; t < TILE_ * TILE_; t += 256) {
        int oy = t >> 5, ox = t & 31;
        float v = sm[oy + 1][ox + 1];
        float m =        sm[oy    ][ox    ];
        m = fmaxf(m,     sm[oy    ][ox + 1]);
        m = fmaxf(m,     sm[oy    ][ox + 2]);
        m = fmaxf(m,     sm[oy + 1][ox    ]);
        m = fmaxf(m,     sm[oy + 1][ox + 2]);
        m = fmaxf(m,     sm[oy + 2][ox    ]);
        m = fmaxf(m,     sm[oy + 2][ox + 1]);
        m = fmaxf(m,     sm[oy + 2][ox + 2]);
        if (v >= m) {
            unsigned int bits = __float_as_uint(v);
            if ((bits >> 18) >= T) {
                unsigned int idx = (unsigned int)((by + oy) * W_ + (bx + ox));
                int p = atomicAdd(&cand_cnt[b], 1);
                if (p < CANDCAP_)
                    cand[(size_t)b * CANDCAP_ + p] =
                        ((unsigned long long)bits << 32) | (0xFFFFFFFFu - idx);
            }
        }
    }
}

// ---- Pass D: per-batch bitonic sort (desc, exact 64-bit key) + emit --------
__global__ __launch_bounds__(1024) void sort_emit_kernel(
    const float* __restrict__ scale, const float* __restrict__ unc,
    const unsigned long long* __restrict__ cand,
    const int* __restrict__ cand_cnt,
    const int* __restrict__ ih_p, const int* __restrict__ iw_p,
    float* __restrict__ out)
{
    __shared__ unsigned long long sc_[CANDCAP_];
    const int b = blockIdx.x, tid = threadIdx.x;

    int n = cand_cnt[b]; if (n > CANDCAP_) n = CANDCAP_;
    for (int i = tid; i < CANDCAP_; i += 1024)
        sc_[i] = (i < n) ? cand[(size_t)b * CANDCAP_ + i] : 0ull;

    for (int kk = 2; kk <= CANDCAP_; kk <<= 1) {
        for (int jj = kk >> 1; jj > 0; jj >>= 1) {
            __syncthreads();
            for (int i = tid; i < CANDCAP_; i += 1024) {
                int ixj = i ^ jj;
                if (ixj > i) {
                    bool desc = ((i & kk) == 0);
                    unsigned long long a = sc_[i], c2 = sc_[ixj];
                    if (desc ? (a < c2) : (a > c2)) { sc_[i] = c2; sc_[ixj] = a; }
                }
            }
        }
    }
    __syncthreads();

    const float fih = (float)(*ih_p);
    const float fiw = (float)(*iw_p);
    float* rois   = out;                       // [B,K,5]
    float* scores = out + (size_t)B_ * K_ * 5; // [B,K]
    float* validf = out + (size_t)B_ * K_ * 6; // [B,K]

    for (int k = tid; k < K_; k += 1024) {
        int o = b * K_ + k;
        unsigned long long key = sc_[k];
        unsigned int bits = (unsigned int)(key >> 32);
        if (bits == 0u) {
            rois[o * 5 + 0] = 0.0f; rois[o * 5 + 1] = 0.0f;
            rois[o * 5 + 2] = 0.0f; rois[o * 5 + 3] = 0.0f;
            rois[o * 5 + 4] = 0.0f;
            scores[o] = 0.0f; validf[o] = 0.0f;
        } else {
            float v = __uint_as_float(bits);
            unsigned int idx = 0xFFFFFFFFu - (unsigned int)(key & 0xFFFFFFFFull);
            int y = (int)(idx >> 9), x = (int)(idx & 511u);
            float cx = ((float)x + 0.5f) * 4.0f;
            float cy = ((float)y + 0.5f) * 4.0f;
            float ss = sigmoid_fast(scale[(size_t)b * HW_ + idx]);
            float su = sigmoid_fast(unc  [(size_t)b * HW_ + idx]);
            float side = (32.0f + ss * 480.0f) * (1.0f + 0.25f * su);
            float half = 0.5f * side;
            float x1 = fminf(fmaxf(cx - half, 0.0f), fiw - 1.0f);
            float y1 = fminf(fmaxf(cy - half, 0.0f), fih - 1.0f);
            float x2 = fminf(fmaxf(cx + half, 1.0f), fiw);
            float y2 = fminf(fmaxf(cy + half, 1.0f), fih);
            rois[o * 5 + 0] = (float)b;
            rois[o * 5 + 1] = x1; rois[o * 5 + 2] = y1;
            rois[o * 5 + 3] = x2; rois[o * 5 + 4] = y2;
            scores[o] = v; validf[o] = 1.0f;
        }
    }
}

extern "C" void kernel_launch(void* const* d_in, const int* in_sizes, int n_in,
                              void* d_out, int out_size, void* d_ws, size_t ws_size,
                              hipStream_t stream) {
    const float* route = (const float*)d_in[0];
    const float* scale = (const float*)d_in[1];
    const float* unc   = (const float*)d_in[2];
    const int*   ih    = (const int*)d_in[3];
    const int*   iw    = (const int*)d_in[4];
    float* out = (float*)d_out;

    // ws: [hist 2MB][thresh 128B][cand_cnt 128B][pad][cand 1MB] ~= 3.1MB total
    char* ws = (char*)d_ws;
    unsigned int* hist   = (unsigned int*)ws;
    const size_t hist_b  = (size_t)B_ * NB_ * 4;
    unsigned int* thresh = (unsigned int*)(ws + hist_b);
    int* cand_cnt        = (int*)(ws + hist_b + 128);
    unsigned long long* cand = (unsigned long long*)(ws + hist_b + 512);

    hipMemsetAsync(d_ws, 0, hist_b + 512, stream);

    dim3 g(W_ / TILE_, H_ / TILE_, B_);
    hist_kernel  <<<g, 256, 0, stream>>>(route, unc, hist);
    thresh_kernel<<<B_, 1024, 0, stream>>>(hist, thresh);
    cand_kernel  <<<g, 256, 0, stream>>>(route, unc, thresh, cand, cand_cnt);
    sort_emit_kernel<<<B_, 1024, 0, stream>>>(scale, unc, cand, cand_cnt,
                                              ih, iw, out);
}

// Round 6
// 352.228 us; speedup vs baseline: 2.1435x; 2.1435x over previous
//
#include <hip/hip_runtime.h>
#include <hip/hip_bf16.h>
#include <math.h>

// H2R detector: score map -> 3x3 NMS peaks -> per-batch top-1000 -> ROIs.
// [B=32,1,512,512] fp32 inputs; out = rois[32,1000,5] ++ scores[32,1000]
// ++ valid[32,1000] = 224000 floats.
//
// Scoring replicates numpy's SIMD (Cephes) fp32 expf op-for-op (verified
// bit-exact in round 5: absmax 0.0). DO NOT alter the score path.
//
// Round 6: single fused pass (score+peak+hist+list) with float4 staging for
// MLP; filter moved into the sort kernel. Round-5 tile kernels were
// latency-bound (VALUBusy 5.9%, HBM 3.5% peak, VGPR=12 -> 1 load in flight).

#define B_   32
#define H_   512
#define W_   512
#define HW_  (H_ * W_)
#define K_   1000
#define NB_  16384      // histogram buckets = float_bits >> 18
#define CANDCAP_ 4096   // candidate sort capacity (power of 2)
#define ROWS_ 8         // output rows per block
#define PBUF_ 1024      // max peaks per 8x512 strip (hard max = 4096/4)
#define PCAP_ 32768     // per-batch peak list capacity (mean ~29.1k, max 64k)

// ---- numpy SIMD (Cephes) fp32 exp replica — bit-exact, do not touch -------
__device__ __forceinline__ float np_expf(float x) {
#pragma clang fp contract(off)
    const float log2e = 1.44269504088896341f;
    float z = x * log2e;
    float m = rintf(z);
    float r = fmaf(m, -0.693359375f, x);
    r = fmaf(m, 2.12194440e-4f, r);
    float r2 = r * r;
    float p = fmaf(1.9875691500e-4f, r, 1.3981999507e-3f);
    p = fmaf(p, r, 8.3334519073e-3f);
    p = fmaf(p, r, 4.1665795894e-2f);
    p = fmaf(p, r, 1.6666665459e-1f);
    p = fmaf(p, r, 5.0000001201e-1f);
    p = fmaf(p, r2, r);
    p = p + 1.0f;
    int mi = (int)m;
    float sc = __int_as_float((127 + mi) << 23);
    return p * sc;
}

__device__ __forceinline__ float sigmoid_np(float x) {
#pragma clang fp contract(off)
    float e = np_expf(-x);
    float d = 1.0f + e;
    return 1.0f / d;
}

__device__ __forceinline__ float score_ref(float r, float u) {
#pragma clang fp contract(off)
    float s  = sigmoid_np(r);
    float s2 = s * s;
    float su = sigmoid_np(u);
    float t  = 0.35f * su;
    float m  = 1.0f - t;
    return s2 * m;
}

__device__ __forceinline__ float sigmoid_fast(float x) {  // box geometry only
    return 1.0f / (1.0f + __expf(-x));
}

// ---- Fused pass: score strip + 3x3 peak test -> peak list + histogram -----
__global__ __launch_bounds__(256) void fused_peak_kernel(
    const float* __restrict__ route, const float* __restrict__ unc,
    unsigned int* __restrict__ hist,
    unsigned long long* __restrict__ plist, int* __restrict__ peak_cnt)
{
    __shared__ float sm[ROWS_ + 2][W_];          // 10x512 = 20 KB
    __shared__ unsigned long long pbuf[PBUF_];   // 8 KB
    __shared__ int lcnt, gbase;

    const int tid   = threadIdx.x;
    const int strip = blockIdx.x;                // 0..63
    const int b     = blockIdx.y;                // 0..31
    const int r0    = strip * ROWS_;
    if (tid == 0) lcnt = 0;

    const float4* rb4 = (const float4*)(route + (size_t)b * HW_);
    const float4* ub4 = (const float4*)(unc   + (size_t)b * HW_);

    // Stage 10 halo rows: 1280 float4s, 5 per thread per input. All 10
    // loads issued before any use -> deep MLP, coalesced 16B/lane.
    float4 rv[5], uv[5];
    int lrow[5], col4[5]; bool ok[5];
    #pragma unroll
    for (int k = 0; k < 5; ++k) {
        int f   = tid + k * 256;                 // 0..1279
        int row = f >> 7;                        // 128 float4 per row
        int gy  = r0 - 1 + row;
        lrow[k] = row; col4[k] = f & 127;
        ok[k]   = (gy >= 0 && gy < H_);
        int cy  = gy < 0 ? 0 : (gy >= H_ ? H_ - 1 : gy);
        rv[k] = rb4[cy * 128 + col4[k]];
        uv[k] = ub4[cy * 128 + col4[k]];
    }
    #pragma unroll
    for (int k = 0; k < 5; ++k) {
        float4 s;
        s.x = score_ref(rv[k].x, uv[k].x);
        s.y = score_ref(rv[k].y, uv[k].y);
        s.z = score_ref(rv[k].z, uv[k].z);
        s.w = score_ref(rv[k].w, uv[k].w);
        if (!ok[k]) { s.x = -INFINITY; s.y = -INFINITY;
                      s.z = -INFINITY; s.w = -INFINITY; }
        *(float4*)&sm[lrow[k]][col4[k] * 4] = s;
    }
    __syncthreads();

    // Peak test: 8x512 interior, 4-pixel groups, 16 px/thread.
    #pragma unroll
    for (int j = 0; j < 4; ++j) {
        int g  = tid + j * 256;                  // 0..1023
        int ly = 1 + (g >> 7);                   // 1..8
        int x0 = (g & 127) * 4;
        int gy = r0 + (ly - 1);
        float w[3][6];
        #pragma unroll
        for (int r = 0; r < 3; ++r) {
            int rr = ly - 1 + r;
            w[r][0] = (x0 > 0) ? sm[rr][x0 - 1] : -INFINITY;
            w[r][1] = sm[rr][x0];
            w[r][2] = sm[rr][x0 + 1];
            w[r][3] = sm[rr][x0 + 2];
            w[r][4] = sm[rr][x0 + 3];
            w[r][5] = (x0 + 4 < W_) ? sm[rr][x0 + 4] : -INFINITY;
        }
        #pragma unroll
        for (int i = 0; i < 4; ++i) {
            float v = w[1][i + 1];
            float m = fmaxf(fmaxf(fmaxf(w[0][i], w[0][i + 1]),
                                  fmaxf(w[0][i + 2], w[1][i])),
                            fmaxf(fmaxf(w[1][i + 2], w[2][i]),
                                  fmaxf(w[2][i + 1], w[2][i + 2])));
            if (v >= m) {
                unsigned int bits = __float_as_uint(v);
                unsigned int idx  = (unsigned int)(gy * W_ + x0 + i);
                int p = atomicAdd(&lcnt, 1);
                if (p < PBUF_)
                    pbuf[p] = ((unsigned long long)bits << 32)
                              | (0xFFFFFFFFu - idx);
                atomicAdd(&hist[b * NB_ + (bits >> 18)], 1u);
            }
        }
    }
    __syncthreads();
    if (tid == 0) {
        int n = lcnt < PBUF_ ? lcnt : PBUF_;
        gbase = atomicAdd(&peak_cnt[b], n);
    }
    __syncthreads();
    int n = lcnt < PBUF_ ? lcnt : PBUF_;
    int base = gbase;
    for (int i = tid; i < n; i += 256) {
        int dst = base + i;
        if (dst < PCAP_) plist[(size_t)b * PCAP_ + dst] = pbuf[i];
    }
}

// ---- Threshold bucket T: smallest T with count(bucket >= T) >= K ----------
__global__ __launch_bounds__(1024) void thresh_kernel(
    const unsigned int* __restrict__ hist, unsigned int* __restrict__ thresh)
{
    __shared__ unsigned int chunk[1024];
    __shared__ int warp_s[16];
    __shared__ int sh_sum, sh_T;

    const int b = blockIdx.x, tid = threadIdx.x;
    const int lane = tid & 63, wid = tid >> 6;
    if (tid == 0) sh_T = 0;

    int total = 0;
    for (int c = NB_ / 1024 - 1; c >= 0; --c) {
        unsigned int hv = hist[b * NB_ + c * 1024 + tid];
        chunk[tid] = hv;
        int v = (int)hv;
        #pragma unroll
        for (int off = 32; off > 0; off >>= 1) v += __shfl_down(v, off, 64);
        if (lane == 0) warp_s[wid] = v;
        __syncthreads();
        if (tid == 0) {
            int s = 0;
            #pragma unroll
            for (int w = 0; w < 16; ++w) s += warp_s[w];
            sh_sum = s;
        }
        __syncthreads();
        int s = sh_sum;
        __syncthreads();
        if (total + s < K_) { total += s; continue; }
        if (tid == 0) {
            int acc = total, t = c * 1024;
            for (int i = 1023; i >= 0; --i) {
                acc += (int)chunk[i];
                if (acc >= K_) { t = c * 1024 + i; break; }
            }
            sh_T = t;
        }
        break;
    }
    __syncthreads();
    if (tid == 0) thresh[b] = (unsigned int)sh_T;
}

// ---- Filter peak list >= T, bitonic sort (desc, 64-bit key), emit ---------
__global__ __launch_bounds__(1024) void sort_emit_kernel(
    const float* __restrict__ scale, const float* __restrict__ unc,
    const unsigned long long* __restrict__ plist,
    const int* __restrict__ peak_cnt,
    const unsigned int* __restrict__ thresh,
    const int* __restrict__ ih_p, const int* __restrict__ iw_p,
    float* __restrict__ out)
{
    __shared__ unsigned long long sc_[CANDCAP_];
    __shared__ int sh_n;
    const int b = blockIdx.x, tid = threadIdx.x;
    if (tid == 0) sh_n = 0;
    __syncthreads();

    const unsigned int T = thresh[b];
    int n = peak_cnt[b]; if (n > PCAP_) n = PCAP_;
    for (int i = tid; i < n; i += 1024) {
        unsigned long long key = plist[(size_t)b * PCAP_ + i];
        unsigned int bits = (unsigned int)(key >> 32);
        if ((bits >> 18) >= T) {
            int p = atomicAdd(&sh_n, 1);
            if (p < CANDCAP_) sc_[p] = key;
        }
    }
    __syncthreads();
    int nc = sh_n; if (nc > CANDCAP_) nc = CANDCAP_;
    for (int i = tid; i < CANDCAP_; i += 1024)
        if (i >= nc) sc_[i] = 0ull;

    for (int kk = 2; kk <= CANDCAP_; kk <<= 1) {
        for (int jj = kk >> 1; jj > 0; jj >>= 1) {
            __syncthreads();
            for (int i = tid; i < CANDCAP_; i += 1024) {
                int ixj = i ^ jj;
                if (ixj > i) {
                    bool desc = ((i & kk) == 0);
                    unsigned long long a = sc_[i], c2 = sc_[ixj];
                    if (desc ? (a < c2) : (a > c2)) { sc_[i] = c2; sc_[ixj] = a; }
                }
            }
        }
    }
    __syncthreads();

    const float fih = (float)(*ih_p);
    const float fiw = (float)(*iw_p);
    float* rois   = out;                       // [B,K,5]
    float* scores = out + (size_t)B_ * K_ * 5; // [B,K]
    float* validf = out + (size_t)B_ * K_ * 6; // [B,K]

    for (int k = tid; k < K_; k += 1024) {
        int o = b * K_ + k;
        unsigned long long key = sc_[k];
        unsigned int bits = (unsigned int)(key >> 32);
        if (bits == 0u) {
            rois[o * 5 + 0] = 0.0f; rois[o * 5 + 1] = 0.0f;
            rois[o * 5 + 2] = 0.0f; rois[o * 5 + 3] = 0.0f;
            rois[o * 5 + 4] = 0.0f;
            scores[o] = 0.0f; validf[o] = 0.0f;
        } else {
            float v = __uint_as_float(bits);
            unsigned int idx = 0xFFFFFFFFu - (unsigned int)(key & 0xFFFFFFFFull);
            int y = (int)(idx >> 9), x = (int)(idx & 511u);
            float cx = ((float)x + 0.5f) * 4.0f;
            float cy = ((float)y + 0.5f) * 4.0f;
            float ss = sigmoid_fast(scale[(size_t)b * HW_ + idx]);
            float su = sigmoid_fast(unc  [(size_t)b * HW_ + idx]);
            float side = (32.0f + ss * 480.0f) * (1.0f + 0.25f * su);
            float half = 0.5f * side;
            float x1 = fminf(fmaxf(cx - half, 0.0f), fiw - 1.0f);
            float y1 = fminf(fmaxf(cy - half, 0.0f), fih - 1.0f);
            float x2 = fminf(fmaxf(cx + half, 1.0f), fiw);
            float y2 = fminf(fmaxf(cy + half, 1.0f), fih);
            rois[o * 5 + 0] = (float)b;
            rois[o * 5 + 1] = x1; rois[o * 5 + 2] = y1;
            rois[o * 5 + 3] = x2; rois[o * 5 + 4] = y2;
            scores[o] = v; validf[o] = 1.0f;
        }
    }
}

extern "C" void kernel_launch(void* const* d_in, const int* in_sizes, int n_in,
                              void* d_out, int out_size, void* d_ws, size_t ws_size,
                              hipStream_t stream) {
    const float* route = (const float*)d_in[0];
    const float* scale = (const float*)d_in[1];
    const float* unc   = (const float*)d_in[2];
    const int*   ih    = (const int*)d_in[3];
    const int*   iw    = (const int*)d_in[4];
    float* out = (float*)d_out;

    // ws: [hist 2MB][thresh 128B][peak_cnt 128B][pad][plist 8MB] ~= 10.1MB
    char* ws = (char*)d_ws;
    unsigned int* hist   = (unsigned int*)ws;
    const size_t hist_b  = (size_t)B_ * NB_ * 4;
    unsigned int* thresh = (unsigned int*)(ws + hist_b);
    int* peak_cnt        = (int*)(ws + hist_b + 128);
    unsigned long long* plist = (unsigned long long*)(ws + hist_b + 512);

    hipMemsetAsync(d_ws, 0, hist_b + 512, stream);

    dim3 g(H_ / ROWS_, B_);   // 64 strips x 32 batches
    fused_peak_kernel<<<g, 256, 0, stream>>>(route, unc, hist, plist, peak_cnt);
    thresh_kernel<<<B_, 1024, 0, stream>>>(hist, thresh);
    sort_emit_kernel<<<B_, 1024, 0, stream>>>(scale, unc, plist, peak_cnt,
                                              thresh, ih, iw, out);
}

// Round 7
// 186.605 us; speedup vs baseline: 4.0459x; 1.8876x over previous
//
#include <hip/hip_runtime.h>
#include <hip/hip_bf16.h>
#include <math.h>

// H2R detector: score map -> 3x3 NMS peaks -> per-batch top-1000 -> ROIs.
// [B=32,1,512,512] fp32 inputs; out = rois[32,1000,5] ++ scores[32,1000]
// ++ valid[32,1000] = 224000 floats.
//
// Scoring replicates numpy's SIMD (Cephes) fp32 expf op-for-op (verified
// bit-exact in rounds 5/6: absmax 0.0). DO NOT alter the score path.
//
// Round 7: (a) 512-thread / 16-row-strip fused kernel, launch_bounds(512,4)
// so the 10-deep float4 load batch stays in flight (r6 VGPR=44 serialized);
// (b) global histogram removed — selection kernel builds a 16-bit-packed
// 16384-bucket histogram in LDS from the peak list, finds T via parallel
// suffix scan, gathers, sorts 2048, emits. 2 kernels + 512B memset total.

#define B_   32
#define H_   512
#define W_   512
#define HW_  (H_ * W_)
#define K_   1000
#define ROWS_ 16        // interior rows per strip
#define THR_  512       // threads per fused block (8 waves)
#define PBUF_ 2048      // hard max peaks per 16x512 strip = 8*256
#define PCAP_ 32768     // per-batch peak list capacity (mean ~29.1k)
#define CAND_ 2048      // candidate sort capacity (power of 2)

// ---- numpy SIMD (Cephes) fp32 exp replica — bit-exact, do not touch -------
__device__ __forceinline__ float np_expf(float x) {
#pragma clang fp contract(off)
    const float log2e = 1.44269504088896341f;
    float z = x * log2e;
    float m = rintf(z);
    float r = fmaf(m, -0.693359375f, x);
    r = fmaf(m, 2.12194440e-4f, r);
    float r2 = r * r;
    float p = fmaf(1.9875691500e-4f, r, 1.3981999507e-3f);
    p = fmaf(p, r, 8.3334519073e-3f);
    p = fmaf(p, r, 4.1665795894e-2f);
    p = fmaf(p, r, 1.6666665459e-1f);
    p = fmaf(p, r, 5.0000001201e-1f);
    p = fmaf(p, r2, r);
    p = p + 1.0f;
    int mi = (int)m;
    float sc = __int_as_float((127 + mi) << 23);
    return p * sc;
}

__device__ __forceinline__ float sigmoid_np(float x) {
#pragma clang fp contract(off)
    float e = np_expf(-x);
    float d = 1.0f + e;
    return 1.0f / d;
}

__device__ __forceinline__ float score_ref(float r, float u) {
#pragma clang fp contract(off)
    float s  = sigmoid_np(r);
    float s2 = s * s;
    float su = sigmoid_np(u);
    float t  = 0.35f * su;
    float m  = 1.0f - t;
    return s2 * m;
}

__device__ __forceinline__ float sigmoid_fast(float x) {  // box geometry only
    return 1.0f / (1.0f + __expf(-x));
}

// ---- Fused pass: score strip + 3x3 peak test -> per-batch peak list -------
__global__ __launch_bounds__(THR_, 4) void fused_peak_kernel(
    const float* __restrict__ route, const float* __restrict__ unc,
    unsigned long long* __restrict__ plist, int* __restrict__ peak_cnt)
{
    __shared__ float sm[ROWS_ + 2][W_];          // 18x512 = 36.9 KB
    __shared__ unsigned long long pbuf[PBUF_];   // 16 KB
    __shared__ int lcnt, gbase;

    const int tid   = threadIdx.x;
    const int strip = blockIdx.x;                // 0..31
    const int b     = blockIdx.y;                // 0..31
    const int r0    = strip * ROWS_;
    if (tid == 0) lcnt = 0;

    const float4* rb4 = (const float4*)(route + (size_t)b * HW_);
    const float4* ub4 = (const float4*)(unc   + (size_t)b * HW_);

    // Stage 18 halo rows: 2304 float4-slots per input, 4.5 per thread.
    // All loads issued before any compute (10 independent float4 loads).
    float4 rv[5], uv[5];
    int lrow[5], c4[5]; bool ok[5], act[5];
    #pragma unroll
    for (int k = 0; k < 5; ++k) {
        int slot = tid + k * THR_;               // 0..2559
        act[k]  = slot < (ROWS_ + 2) * 128;      // 2304 valid slots
        int row = slot >> 7;                     // 128 float4 per row
        int gy  = r0 - 1 + row;
        lrow[k] = row; c4[k] = slot & 127;
        ok[k]   = (gy >= 0 && gy < H_);
        int cy  = gy < 0 ? 0 : (gy >= H_ ? H_ - 1 : gy);
        if (act[k]) {
            rv[k] = rb4[cy * 128 + c4[k]];
            uv[k] = ub4[cy * 128 + c4[k]];
        }
    }
    #pragma unroll
    for (int k = 0; k < 5; ++k) {
        if (!act[k]) continue;
        float4 s;
        s.x = score_ref(rv[k].x, uv[k].x);
        s.y = score_ref(rv[k].y, uv[k].y);
        s.z = score_ref(rv[k].z, uv[k].z);
        s.w = score_ref(rv[k].w, uv[k].w);
        if (!ok[k]) { s.x = -INFINITY; s.y = -INFINITY;
                      s.z = -INFINITY; s.w = -INFINITY; }
        *(float4*)&sm[lrow[k]][c4[k] * 4] = s;
    }
    __syncthreads();

    // Peak test: 16x512 interior, 4-px groups, 16 px/thread.
    #pragma unroll
    for (int j = 0; j < 4; ++j) {
        int g  = tid + j * THR_;                 // 0..2047
        int ly = 1 + (g >> 7);                   // 1..16
        int x0 = (g & 127) * 4;
        int gy = r0 + (ly - 1);
        float w[3][6];
        #pragma unroll
        for (int r = 0; r < 3; ++r) {
            int rr = ly - 1 + r;
            w[r][0] = (x0 > 0) ? sm[rr][x0 - 1] : -INFINITY;
            w[r][1] = sm[rr][x0];
            w[r][2] = sm[rr][x0 + 1];
            w[r][3] = sm[rr][x0 + 2];
            w[r][4] = sm[rr][x0 + 3];
            w[r][5] = (x0 + 4 < W_) ? sm[rr][x0 + 4] : -INFINITY;
        }
        #pragma unroll
        for (int i = 0; i < 4; ++i) {
            float v = w[1][i + 1];
            float m = fmaxf(fmaxf(fmaxf(w[0][i], w[0][i + 1]),
                                  fmaxf(w[0][i + 2], w[1][i])),
                            fmaxf(fmaxf(w[1][i + 2], w[2][i]),
                                  fmaxf(w[2][i + 1], w[2][i + 2])));
            if (v >= m) {
                unsigned int bits = __float_as_uint(v);
                unsigned int idx  = (unsigned int)(gy * W_ + x0 + i);
                int p = atomicAdd(&lcnt, 1);
                if (p < PBUF_)
                    pbuf[p] = ((unsigned long long)bits << 32)
                              | (0xFFFFFFFFu - idx);
            }
        }
    }
    __syncthreads();
    if (tid == 0) {
        int n = lcnt < PBUF_ ? lcnt : PBUF_;
        gbase = atomicAdd(&peak_cnt[b], n);
    }
    __syncthreads();
    int n = lcnt < PBUF_ ? lcnt : PBUF_;
    int base = gbase;
    for (int i = tid; i < n; i += THR_) {
        int dst = base + i;
        if (dst < PCAP_) plist[(size_t)b * PCAP_ + dst] = pbuf[i];
    }
}

// ---- Select: LDS hist -> threshold T -> gather -> bitonic sort -> emit ----
__global__ __launch_bounds__(1024) void select_kernel(
    const float* __restrict__ scale, const float* __restrict__ unc,
    const unsigned long long* __restrict__ plist,
    const int* __restrict__ peak_cnt,
    const int* __restrict__ ih_p, const int* __restrict__ iw_p,
    float* __restrict__ out)
{
    __shared__ unsigned int h16[8192];           // 16384 buckets, 16-bit packed
    __shared__ unsigned long long cand[CAND_];   // 16 KB
    __shared__ unsigned int ssum[1024];          // 4 KB (suffix scan)
    __shared__ int warp_s[16];
    __shared__ int sh_sum, sh_T, sh_n;

    const int b = blockIdx.x, tid = threadIdx.x;
    const int lane = tid & 63, wid = tid >> 6;
    if (tid == 0) { sh_T = 0; sh_n = 0; }
    for (int i = tid; i < 8192; i += 1024) h16[i] = 0u;
    __syncthreads();

    int pc = peak_cnt[b]; if (pc > PCAP_) pc = PCAP_;
    const unsigned long long* pl = plist + (size_t)b * PCAP_;

    // Phase 1: LDS histogram (bucket = score_bits >> 18, counts fit 16 bits)
    for (int i = tid; i < pc; i += 1024) {
        unsigned int bits = (unsigned int)(pl[i] >> 32);
        unsigned int bkt  = bits >> 18;
        atomicAdd(&h16[bkt >> 1], 1u << ((bkt & 1) * 16));
    }
    __syncthreads();

    // Phase 2: T = smallest bucket with count(bucket >= T) >= K
    int total = 0;
    for (int c = 15; c >= 0; --c) {
        int bucket = c * 1024 + tid;
        unsigned int cnt = (h16[bucket >> 1] >> ((bucket & 1) * 16)) & 0xFFFFu;
        int v = (int)cnt;
        #pragma unroll
        for (int off = 32; off > 0; off >>= 1) v += __shfl_down(v, off, 64);
        if (lane == 0) warp_s[wid] = v;
        __syncthreads();
        if (tid == 0) {
            int s = 0;
            #pragma unroll
            for (int w = 0; w < 16; ++w) s += warp_s[w];
            sh_sum = s;
        }
        __syncthreads();
        int s = sh_sum;
        __syncthreads();
        if (total + s < K_) { total += s; continue; }
        // crossing chunk: parallel suffix scan over its 1024 buckets
        ssum[tid] = cnt;
        __syncthreads();
        for (int off = 1; off < 1024; off <<= 1) {
            unsigned int vv = (tid + off < 1024) ? ssum[tid + off] : 0u;
            __syncthreads();
            ssum[tid] += vv;
            __syncthreads();
        }
        bool cond  = (total + (int)ssum[tid]) >= K_;
        bool cnext = (tid == 1023) ? false
                     : ((total + (int)ssum[tid + 1]) >= K_);
        if (cond && !cnext) sh_T = c * 1024 + tid;   // largest qualifying
        __syncthreads();
        break;
    }
    const unsigned int T = (unsigned int)sh_T;

    // Phase 3: gather candidates with bucket >= T
    for (int i = tid; i < pc; i += 1024) {
        unsigned long long key = pl[i];
        if ((((unsigned int)(key >> 32)) >> 18) >= T) {
            int p = atomicAdd(&sh_n, 1);
            if (p < CAND_) cand[p] = key;
        }
    }
    __syncthreads();
    int nc = sh_n; if (nc > CAND_) nc = CAND_;
    for (int i = tid; i < CAND_; i += 1024)
        if (i >= nc) cand[i] = 0ull;

    // Phase 4: bitonic sort 2048 (desc, exact 64-bit key)
    for (int kk = 2; kk <= CAND_; kk <<= 1) {
        for (int jj = kk >> 1; jj > 0; jj >>= 1) {
            __syncthreads();
            for (int i = tid; i < CAND_; i += 1024) {
                int ixj = i ^ jj;
                if (ixj > i) {
                    bool desc = ((i & kk) == 0);
                    unsigned long long a = cand[i], c2 = cand[ixj];
                    if (desc ? (a < c2) : (a > c2)) { cand[i] = c2; cand[ixj] = a; }
                }
            }
        }
    }
    __syncthreads();

    // Phase 5: emit top-K (identical to round-6 verified path)
    const float fih = (float)(*ih_p);
    const float fiw = (float)(*iw_p);
    float* rois   = out;                       // [B,K,5]
    float* scores = out + (size_t)B_ * K_ * 5; // [B,K]
    float* validf = out + (size_t)B_ * K_ * 6; // [B,K]

    for (int k = tid; k < K_; k += 1024) {
        int o = b * K_ + k;
        unsigned long long key = cand[k];
        unsigned int bits = (unsigned int)(key >> 32);
        if (bits == 0u) {
            rois[o * 5 + 0] = 0.0f; rois[o * 5 + 1] = 0.0f;
            rois[o * 5 + 2] = 0.0f; rois[o * 5 + 3] = 0.0f;
            rois[o * 5 + 4] = 0.0f;
            scores[o] = 0.0f; validf[o] = 0.0f;
        } else {
            float v = __uint_as_float(bits);
            unsigned int idx = 0xFFFFFFFFu - (unsigned int)(key & 0xFFFFFFFFull);
            int y = (int)(idx >> 9), x = (int)(idx & 511u);
            float cx = ((float)x + 0.5f) * 4.0f;
            float cy = ((float)y + 0.5f) * 4.0f;
            float ss = sigmoid_fast(scale[(size_t)b * HW_ + idx]);
            float su = sigmoid_fast(unc  [(size_t)b * HW_ + idx]);
            float side = (32.0f + ss * 480.0f) * (1.0f + 0.25f * su);
            float half = 0.5f * side;
            float x1 = fminf(fmaxf(cx - half, 0.0f), fiw - 1.0f);
            float y1 = fminf(fmaxf(cy - half, 0.0f), fih - 1.0f);
            float x2 = fminf(fmaxf(cx + half, 1.0f), fiw);
            float y2 = fminf(fmaxf(cy + half, 1.0f), fih);
            rois[o * 5 + 0] = (float)b;
            rois[o * 5 + 1] = x1; rois[o * 5 + 2] = y1;
            rois[o * 5 + 3] = x2; rois[o * 5 + 4] = y2;
            scores[o] = v; validf[o] = 1.0f;
        }
    }
}

extern "C" void kernel_launch(void* const* d_in, const int* in_sizes, int n_in,
                              void* d_out, int out_size, void* d_ws, size_t ws_size,
                              hipStream_t stream) {
    const float* route = (const float*)d_in[0];
    const float* scale = (const float*)d_in[1];
    const float* unc   = (const float*)d_in[2];
    const int*   ih    = (const int*)d_in[3];
    const int*   iw    = (const int*)d_in[4];
    float* out = (float*)d_out;

    // ws: [peak_cnt 128B][pad to 512][plist 32*32768*8 = 8MB]
    char* ws = (char*)d_ws;
    int* peak_cnt = (int*)ws;
    unsigned long long* plist = (unsigned long long*)(ws + 512);

    hipMemsetAsync(d_ws, 0, 512, stream);

    dim3 g(H_ / ROWS_, B_);   // 32 strips x 32 batches
    fused_peak_kernel<<<g, THR_, 0, stream>>>(route, unc, plist, peak_cnt);
    select_kernel<<<B_, 1024, 0, stream>>>(scale, unc, plist, peak_cnt,
                                           ih, iw, out);
}

// Round 8
// 180.962 us; speedup vs baseline: 4.1721x; 1.0312x over previous
//
#include <hip/hip_runtime.h>
#include <hip/hip_bf16.h>
#include <math.h>

// H2R detector: score map -> 3x3 NMS peaks -> per-batch top-1000 -> ROIs.
// [B=32,1,512,512] fp32 inputs; out = rois[32,1000,5] ++ scores[32,1000]
// ++ valid[32,1000] = 224000 floats.
//
// Scoring replicates numpy's SIMD (Cephes) fp32 expf op-for-op (verified
// bit-exact rounds 5-7: absmax 0.0). DO NOT alter score or emit paths.
//
// Round 8: select kernel restructured — 4096-bucket LDS hist (scores < 1.0),
// wave0-only threshold scan (no block barriers), two-level refinement so the
// bitonic usually sorts 1024 not 2048; pair-indexed bitonic. Fused kernel
// peak test vectorized (float4 LDS reads, column-max form).

#define B_   32
#define H_   512
#define W_   512
#define HW_  (H_ * W_)
#define K_   1000
#define ROWS_ 16        // interior rows per strip
#define THR_  512       // threads per fused block (8 waves)
#define PBUF_ 2048      // hard max peaks per 16x512 strip
#define PCAP_ 32768     // per-batch peak list capacity (mean ~29.1k)
#define CAND_ 2048      // candidate buffer (power of 2)
#define NBUK_ 4096      // score buckets = bits >> 18 (score < 1.0)

// ---- numpy SIMD (Cephes) fp32 exp replica — bit-exact, do not touch -------
__device__ __forceinline__ float np_expf(float x) {
#pragma clang fp contract(off)
    const float log2e = 1.44269504088896341f;
    float z = x * log2e;
    float m = rintf(z);
    float r = fmaf(m, -0.693359375f, x);
    r = fmaf(m, 2.12194440e-4f, r);
    float r2 = r * r;
    float p = fmaf(1.9875691500e-4f, r, 1.3981999507e-3f);
    p = fmaf(p, r, 8.3334519073e-3f);
    p = fmaf(p, r, 4.1665795894e-2f);
    p = fmaf(p, r, 1.6666665459e-1f);
    p = fmaf(p, r, 5.0000001201e-1f);
    p = fmaf(p, r2, r);
    p = p + 1.0f;
    int mi = (int)m;
    float sc = __int_as_float((127 + mi) << 23);
    return p * sc;
}

__device__ __forceinline__ float sigmoid_np(float x) {
#pragma clang fp contract(off)
    float e = np_expf(-x);
    float d = 1.0f + e;
    return 1.0f / d;
}

__device__ __forceinline__ float score_ref(float r, float u) {
#pragma clang fp contract(off)
    float s  = sigmoid_np(r);
    float s2 = s * s;
    float su = sigmoid_np(u);
    float t  = 0.35f * su;
    float m  = 1.0f - t;
    return s2 * m;
}

__device__ __forceinline__ float sigmoid_fast(float x) {  // box geometry only
    return 1.0f / (1.0f + __expf(-x));
}

// ---- Fused pass: score strip + 3x3 peak test -> per-batch peak list -------
__global__ __launch_bounds__(THR_, 4) void fused_peak_kernel(
    const float* __restrict__ route, const float* __restrict__ unc,
    unsigned long long* __restrict__ plist, int* __restrict__ peak_cnt)
{
    __shared__ float sm[ROWS_ + 2][W_];          // 18x512 = 36.9 KB
    __shared__ unsigned long long pbuf[PBUF_];   // 16 KB
    __shared__ int lcnt, gbase;

    const int tid   = threadIdx.x;
    const int strip = blockIdx.x;                // 0..31
    const int b     = blockIdx.y;                // 0..31
    const int r0    = strip * ROWS_;
    if (tid == 0) lcnt = 0;

    const float4* rb4 = (const float4*)(route + (size_t)b * HW_);
    const float4* ub4 = (const float4*)(unc   + (size_t)b * HW_);

    // Stage 18 halo rows: 2304 float4-slots per input, 4.5 per thread.
    float4 rv[5], uv[5];
    int lrow[5], c4[5]; bool ok[5], act[5];
    #pragma unroll
    for (int k = 0; k < 5; ++k) {
        int slot = tid + k * THR_;               // 0..2559
        act[k]  = slot < (ROWS_ + 2) * 128;      // 2304 valid slots
        int row = slot >> 7;
        int gy  = r0 - 1 + row;
        lrow[k] = row; c4[k] = slot & 127;
        ok[k]   = (gy >= 0 && gy < H_);
        int cy  = gy < 0 ? 0 : (gy >= H_ ? H_ - 1 : gy);
        if (act[k]) {
            rv[k] = rb4[cy * 128 + c4[k]];
            uv[k] = ub4[cy * 128 + c4[k]];
        }
    }
    #pragma unroll
    for (int k = 0; k < 5; ++k) {
        if (!act[k]) continue;
        float4 s;
        s.x = score_ref(rv[k].x, uv[k].x);
        s.y = score_ref(rv[k].y, uv[k].y);
        s.z = score_ref(rv[k].z, uv[k].z);
        s.w = score_ref(rv[k].w, uv[k].w);
        if (!ok[k]) { s.x = -INFINITY; s.y = -INFINITY;
                      s.z = -INFINITY; s.w = -INFINITY; }
        *(float4*)&sm[lrow[k]][c4[k] * 4] = s;
    }
    __syncthreads();

    // Peak test: 16x512 interior, 4-px groups via float4 reads + column max.
    #pragma unroll
    for (int j = 0; j < 4; ++j) {
        int g  = tid + j * THR_;                 // 0..2047
        int ly = 1 + (g >> 7);                   // 1..16
        int x0 = (g & 127) * 4;
        int gy = r0 + (ly - 1);
        float4 q0 = *(const float4*)&sm[ly - 1][x0];
        float4 q1 = *(const float4*)&sm[ly    ][x0];
        float4 q2 = *(const float4*)&sm[ly + 1][x0];
        bool hasL = (x0 > 0), hasR = (x0 + 4 < W_);
        float l0 = hasL ? sm[ly - 1][x0 - 1] : -INFINITY;
        float l1 = hasL ? sm[ly    ][x0 - 1] : -INFINITY;
        float l2 = hasL ? sm[ly + 1][x0 - 1] : -INFINITY;
        float e0 = hasR ? sm[ly - 1][x0 + 4] : -INFINITY;
        float e1 = hasR ? sm[ly    ][x0 + 4] : -INFINITY;
        float e2 = hasR ? sm[ly + 1][x0 + 4] : -INFINITY;
        // columns c=-1..4: full3 = max over 3 rows; tb = top+bottom only
        float f_m1 = fmaxf(l0, fmaxf(l1, l2));
        float f_0  = fmaxf(q0.x, fmaxf(q1.x, q2.x));
        float f_1  = fmaxf(q0.y, fmaxf(q1.y, q2.y));
        float f_2  = fmaxf(q0.z, fmaxf(q1.z, q2.z));
        float f_3  = fmaxf(q0.w, fmaxf(q1.w, q2.w));
        float f_4  = fmaxf(e0, fmaxf(e1, e2));
        float tb0  = fmaxf(q0.x, q2.x);
        float tb1  = fmaxf(q0.y, q2.y);
        float tb2  = fmaxf(q0.z, q2.z);
        float tb3  = fmaxf(q0.w, q2.w);
        float vv[4] = { q1.x, q1.y, q1.z, q1.w };
        float mm[4];
        mm[0] = fmaxf(fmaxf(f_m1, f_1), tb0);
        mm[1] = fmaxf(fmaxf(f_0,  f_2), tb1);
        mm[2] = fmaxf(fmaxf(f_1,  f_3), tb2);
        mm[3] = fmaxf(fmaxf(f_2,  f_4), tb3);
        #pragma unroll
        for (int i = 0; i < 4; ++i) {
            if (vv[i] >= mm[i]) {
                unsigned int bits = __float_as_uint(vv[i]);
                unsigned int idx  = (unsigned int)(gy * W_ + x0 + i);
                int p = atomicAdd(&lcnt, 1);
                if (p < PBUF_)
                    pbuf[p] = ((unsigned long long)bits << 32)
                              | (0xFFFFFFFFu - idx);
            }
        }
    }
    __syncthreads();
    if (tid == 0) {
        int n = lcnt < PBUF_ ? lcnt : PBUF_;
        gbase = atomicAdd(&peak_cnt[b], n);
    }
    __syncthreads();
    int n = lcnt < PBUF_ ? lcnt : PBUF_;
    int base = gbase;
    for (int i = tid; i < n; i += THR_) {
        int dst = base + i;
        if (dst < PCAP_) plist[(size_t)b * PCAP_ + dst] = pbuf[i];
    }
}

// ---- Select: LDS hist -> wave0 threshold (+refine) -> gather -> sort ------
__global__ __launch_bounds__(1024) void select_kernel(
    const float* __restrict__ scale, const float* __restrict__ unc,
    const unsigned long long* __restrict__ plist,
    const int* __restrict__ peak_cnt,
    const int* __restrict__ ih_p, const int* __restrict__ iw_p,
    float* __restrict__ out)
{
    __shared__ unsigned int h16[NBUK_ / 2];      // 4096 buckets, 16-bit packed
    __shared__ unsigned long long cand[CAND_];   // 16 KB
    __shared__ int sh_T, sh_T2, sh_ref, sh_n;

    const int b = blockIdx.x, tid = threadIdx.x;
    const int lane = tid & 63, wid = tid >> 6;
    if (tid == 0) { sh_T = 0; sh_T2 = 0; sh_ref = 0; sh_n = 0; }
    for (int i = tid; i < NBUK_ / 2; i += 1024) h16[i] = 0u;
    __syncthreads();

    int pc = peak_cnt[b]; if (pc > PCAP_) pc = PCAP_;
    const unsigned long long* pl = plist + (size_t)b * PCAP_;

    // Phase 1: histogram on bucket = bits>>18 (score in [0,1) -> < 4096)
    for (int i = tid; i < pc; i += 1024) {
        unsigned int bkt = ((unsigned int)(pl[i] >> 32)) >> 18;
        atomicAdd(&h16[bkt >> 1], 1u << ((bkt & 1) * 16));
    }
    __syncthreads();

    // Phase 2 (wave 0 only): largest bucket T with count(>=T) >= K;
    // A = count strictly above T; refine if A + cnt_T > 1024.
    if (wid == 0) {
        int total = 0;
        for (int c = NBUK_ / 64 - 1; c >= 0; --c) {
            int bucket = c * 64 + lane;
            int cnt = (int)((h16[bucket >> 1] >> ((bucket & 1) * 16)) & 0xFFFFu);
            int s = cnt;
            #pragma unroll
            for (int off = 32; off > 0; off >>= 1) s += __shfl_down(s, off, 64);
            s = __shfl(s, 0, 64);
            if (total + s < K_) { total += s; continue; }
            int suf = cnt;
            #pragma unroll
            for (int off = 1; off < 64; off <<= 1) {
                int o = __shfl_down(suf, off, 64);
                suf += (lane + off < 64) ? o : 0;
            }
            bool cond = (total + suf) >= K_;
            unsigned long long mask = __ballot(cond);
            int ls = 63 - __builtin_clzll(mask);
            int sufs = __shfl(suf, ls, 64);
            int cnts = __shfl(cnt, ls, 64);
            if (lane == 0) {
                sh_T = c * 64 + ls;
                int A = total + sufs - cnts;
                sh_ref = (A + cnts > 1024) ? (0x40000000 | A) : 0;
            }
            break;
        }
    }
    __syncthreads();
    const unsigned int T = (unsigned int)sh_T;
    const int refflag = sh_ref;
    const int refined = (refflag >> 30) & 1;
    const int A = refflag & 0x3FFFFFFF;

    if (refined) {
        // re-zero hist, histogram bucket==T keys on next 12 bits
        for (int i = tid; i < NBUK_ / 2; i += 1024) h16[i] = 0u;
        __syncthreads();
        for (int i = tid; i < pc; i += 1024) {
            unsigned int bits = (unsigned int)(pl[i] >> 32);
            if ((bits >> 18) == T) {
                unsigned int sb = (bits >> 6) & 0xFFFu;
                atomicAdd(&h16[sb >> 1], 1u << ((sb & 1) * 16));
            }
        }
        __syncthreads();
        if (wid == 0) {
            int total = A;
            for (int c = NBUK_ / 64 - 1; c >= 0; --c) {
                int bucket = c * 64 + lane;
                int cnt = (int)((h16[bucket >> 1] >> ((bucket & 1) * 16)) & 0xFFFFu);
                int s = cnt;
                #pragma unroll
                for (int off = 32; off > 0; off >>= 1) s += __shfl_down(s, off, 64);
                s = __shfl(s, 0, 64);
                if (total + s < K_) { total += s; continue; }
                int suf = cnt;
                #pragma unroll
                for (int off = 1; off < 64; off <<= 1) {
                    int o = __shfl_down(suf, off, 64);
                    suf += (lane + off < 64) ? o : 0;
                }
                bool cond = (total + suf) >= K_;
                unsigned long long mask = __ballot(cond);
                int ls = 63 - __builtin_clzll(mask);
                if (lane == 0) sh_T2 = c * 64 + ls;
                break;
            }
        }
        __syncthreads();
    }
    const unsigned int T2 = (unsigned int)sh_T2;

    // Phase 3: gather candidates
    for (int i = tid; i < pc; i += 1024) {
        unsigned long long key = pl[i];
        unsigned int bits = (unsigned int)(key >> 32);
        unsigned int bkt  = bits >> 18;
        bool take = (bkt > T) ||
                    (bkt == T && (!refined || (((bits >> 6) & 0xFFFu) >= T2)));
        if (take) {
            int p = atomicAdd(&sh_n, 1);
            if (p < CAND_) cand[p] = key;
        }
    }
    __syncthreads();
    int nc = sh_n; if (nc > CAND_) nc = CAND_;
    int sortN = (nc <= 1024) ? 1024 : CAND_;
    for (int i = tid; i < sortN; i += 1024)
        if (i >= nc) cand[i] = 0ull;

    // Phase 4: pair-indexed bitonic sort (desc, exact 64-bit key)
    for (int kk = 2; kk <= sortN; kk <<= 1) {
        for (int jj = kk >> 1; jj > 0; jj >>= 1) {
            __syncthreads();
            for (int p = tid; p < (sortN >> 1); p += 1024) {
                int i   = ((p & ~(jj - 1)) << 1) | (p & (jj - 1));
                int ixj = i | jj;
                bool desc = ((i & kk) == 0);
                unsigned long long a = cand[i], c2 = cand[ixj];
                if (desc ? (a < c2) : (a > c2)) { cand[i] = c2; cand[ixj] = a; }
            }
        }
    }
    __syncthreads();

    // Phase 5: emit top-K (identical to verified path)
    const float fih = (float)(*ih_p);
    const float fiw = (float)(*iw_p);
    float* rois   = out;                       // [B,K,5]
    float* scores = out + (size_t)B_ * K_ * 5; // [B,K]
    float* validf = out + (size_t)B_ * K_ * 6; // [B,K]

    for (int k = tid; k < K_; k += 1024) {
        int o = b * K_ + k;
        unsigned long long key = cand[k];
        unsigned int bits = (unsigned int)(key >> 32);
        if (bits == 0u) {
            rois[o * 5 + 0] = 0.0f; rois[o * 5 + 1] = 0.0f;
            rois[o * 5 + 2] = 0.0f; rois[o * 5 + 3] = 0.0f;
            rois[o * 5 + 4] = 0.0f;
            scores[o] = 0.0f; validf[o] = 0.0f;
        } else {
            float v = __uint_as_float(bits);
            unsigned int idx = 0xFFFFFFFFu - (unsigned int)(key & 0xFFFFFFFFull);
            int y = (int)(idx >> 9), x = (int)(idx & 511u);
            float cx = ((float)x + 0.5f) * 4.0f;
            float cy = ((float)y + 0.5f) * 4.0f;
            float ss = sigmoid_fast(scale[(size_t)b * HW_ + idx]);
            float su = sigmoid_fast(unc  [(size_t)b * HW_ + idx]);
            float side = (32.0f + ss * 480.0f) * (1.0f + 0.25f * su);
            float half = 0.5f * side;
            float x1 = fminf(fmaxf(cx - half, 0.0f), fiw - 1.0f);
            float y1 = fminf(fmaxf(cy - half, 0.0f), fih - 1.0f);
            float x2 = fminf(fmaxf(cx + half, 1.0f), fiw);
            float y2 = fminf(fmaxf(cy + half, 1.0f), fih);
            rois[o * 5 + 0] = (float)b;
            rois[o * 5 + 1] = x1; rois[o * 5 + 2] = y1;
            rois[o * 5 + 3] = x2; rois[o * 5 + 4] = y2;
            scores[o] = v; validf[o] = 1.0f;
        }
    }
}

extern "C" void kernel_launch(void* const* d_in, const int* in_sizes, int n_in,
                              void* d_out, int out_size, void* d_ws, size_t ws_size,
                              hipStream_t stream) {
    const float* route = (const float*)d_in[0];
    const float* scale = (const float*)d_in[1];
    const float* unc   = (const float*)d_in[2];
    const int*   ih    = (const int*)d_in[3];
    const int*   iw    = (const int*)d_in[4];
    float* out = (float*)d_out;

    // ws: [peak_cnt 128B][pad to 512][plist 32*32768*8 = 8MB]
    char* ws = (char*)d_ws;
    int* peak_cnt = (int*)ws;
    unsigned long long* plist = (unsigned long long*)(ws + 512);

    hipMemsetAsync(d_ws, 0, 512, stream);

    dim3 g(H_ / ROWS_, B_);   // 32 strips x 32 batches
    fused_peak_kernel<<<g, THR_, 0, stream>>>(route, unc, plist, peak_cnt);
    select_kernel<<<B_, 1024, 0, stream>>>(scale, unc, plist, peak_cnt,
                                           ih, iw, out);
}